// Round 5
// baseline (2535.465 us; speedup 1.0000x reference)
//
#include <hip/hip_runtime.h>

// ---------------- problem constants ----------------
#define V_CODES 8192
#define D_DIM   256
#define SPATIAL 4096            // 16*16*16
#define M_ROWS  32768           // 8 * 4096
#define NELEM   8388608         // M_ROWS * D_DIM

static constexpr float GAMMA_F = 0.99f;
static constexpr float OMG_F   = (float)(1.0 - 0.99);
static constexpr float EPS_F   = 1e-7f;
static constexpr float VEPS_F  = (float)(8192 * 1e-7);

// output layout (floats), concatenated in reference return order
static constexpr size_t OFF_QUANT = 0;            // 8388608  quant_st
static constexpr size_t OFF_IDX   = 8388608;      // 32768    enc_idx (stored as float)
static constexpr size_t OFF_QDIFF = 8421376;      // 1        quant_diff
static constexpr size_t OFF_NN    = 8421377;      // 8192     new_N
static constexpr size_t OFF_ZAVG  = 8429569;      // 2097152  new_z_avg
static constexpr size_t OFF_W     = 10526721;     // 2097152  new_weight

typedef _Float16 f16x8 __attribute__((ext_vector_type(8)));
typedef float    f32x4 __attribute__((ext_vector_type(4)));

// async global->LDS, 16B per lane; LDS dest is wave-uniform base + lane*16
#define GLL(gp, lp) __builtin_amdgcn_global_load_lds( \
    (const __attribute__((address_space(1))) unsigned int*)(gp), \
    (__attribute__((address_space(3))) unsigned int*)(lp), 16, 0, 0)

// ---------------- K0c: split W into fp16 hi/lo planes + fused row norms ----------------
__global__ void k_split_w(const float* __restrict__ W, _Float16* __restrict__ Wh,
                          _Float16* __restrict__ Wl, float* __restrict__ wnorm) {
    int t = blockIdx.x * 256 + threadIdx.x;
    size_t i8 = (size_t)t * 8;
    float4 a = *(const float4*)(W + i8);
    float4 b = *(const float4*)(W + i8 + 4);
    float v[8] = {a.x, a.y, a.z, a.w, b.x, b.y, b.z, b.w};
    f16x8 hi, lo;
    float s = 0.0f;
    #pragma unroll
    for (int j = 0; j < 8; j++) {
        _Float16 h = (_Float16)v[j];
        hi[j] = h;
        lo[j] = (_Float16)(v[j] - (float)h);
        s = fmaf(v[j], v[j], s);
    }
    *(f16x8*)(Wh + i8) = hi;
    *(f16x8*)(Wl + i8) = lo;
    #pragma unroll
    for (int msk = 1; msk < 32; msk <<= 1) s += __shfl_xor(s, msk, 64);
    if ((threadIdx.x & 31) == 0) wnorm[t >> 5] = s;
}

// ---------------- K0d: split + transpose X (b,k,sp) -> Xh/Xl (m, k) row-major ----------------
__global__ void k_split_x(const float* __restrict__ X, _Float16* __restrict__ Xh,
                          _Float16* __restrict__ Xl) {
    int bid  = blockIdx.x;            // 1024 blocks
    int lane = threadIdx.x & 63;
    int kg   = (bid & 1) * 4 + (threadIdx.x >> 6);   // 0..7 -> k base kg*32
    int m    = (bid >> 1) * 64 + lane;
    int b  = m >> 12;
    int sp = m & 4095;
    const float* src = X + (size_t)b * (D_DIM * SPATIAL) + (size_t)(kg * 32) * SPATIAL + sp;
    float v[32];
    #pragma unroll
    for (int j = 0; j < 32; j++) v[j] = src[(size_t)j * SPATIAL];   // coalesced across lanes
    _Float16* dh = Xh + (size_t)m * D_DIM + kg * 32;
    _Float16* dl = Xl + (size_t)m * D_DIM + kg * 32;
    #pragma unroll
    for (int c = 0; c < 4; c++) {
        f16x8 hi, lo;
        #pragma unroll
        for (int j = 0; j < 8; j++) {
            float x = v[c * 8 + j];
            _Float16 h = (_Float16)x;
            hi[j] = h;
            lo[j] = (_Float16)(x - (float)h);
        }
        *(f16x8*)(dh + c * 8) = hi;
        *(f16x8*)(dl + c * 8) = lo;
    }
}

// ---------------- K1: MFMA distance GEMM + argmin, two-sweep low-register form ----------------
// sweep1: acc += Ah*Bh + Ah*Bl ; sweep2: acc += Al*Bh  (same AGPR acc)
__device__ inline unsigned long long packkey(float s, int v) {
    unsigned u = __float_as_uint(s);
    u = (u & 0x80000000u) ? ~u : (u | 0x80000000u);
    return ((unsigned long long)u << 32) | (unsigned)v;
}

__global__ __launch_bounds__(256, 4) void k_mfma_argmin(
        const _Float16* __restrict__ Xh, const _Float16* __restrict__ Xl,
        const _Float16* __restrict__ Wh, const _Float16* __restrict__ Wl,
        const float* __restrict__ wnorm, unsigned long long* __restrict__ best) {
    // 3 LDS regions x 8 KB; region = 8 subtiles x 1 KB (16 rows x 32 k, fragment order)
    __shared__ __align__(16) _Float16 lds[12288];
    const int tid  = threadIdx.x;
    const int wid  = tid >> 6;
    const int lane = tid & 63;
    const int wy = wid >> 1, wx = wid & 1;
    const int lrow = lane & 15, lq = lane >> 4;
    const int m0 = blockIdx.y * 128;
    const int v0 = blockIdx.x * 128;

    f32x4 acc[4][4] = {};

    // ---- sweep 1: stage Ah(r0) Bh(r1) Bl(r2), 6 GLL/wave ----
    {
        const _Float16* g1[6];
        #pragma unroll
        for (int j = 0; j < 6; j++) {
            int s = wid * 6 + j;          // 0..23
            int plane = s >> 3;           // 0 Ah, 1 Bh, 2 Bl
            int sub = s & 7;
            const _Float16* P = plane == 0 ? Xh : (plane == 1 ? Wh : Wl);
            int row = (plane == 0 ? m0 : v0) + sub * 16 + lrow;
            g1[j] = P + (size_t)row * D_DIM + lq * 8;
        }
        for (int k0 = 0; k0 < D_DIM; k0 += 32) {
            __syncthreads();
            #pragma unroll
            for (int j = 0; j < 6; j++)
                GLL(g1[j] + k0, &lds[(wid * 6 + j) * 512]);
            __syncthreads();
            f16x8 ah[4];
            #pragma unroll
            for (int i = 0; i < 4; i++)
                ah[i] = *(const f16x8*)&lds[(wy * 4 + i) * 512 + lane * 8];
            #pragma unroll
            for (int vi = 0; vi < 4; vi++) {
                f16x8 bh = *(const f16x8*)&lds[(8  + wx * 4 + vi) * 512 + lane * 8];
                f16x8 bl = *(const f16x8*)&lds[(16 + wx * 4 + vi) * 512 + lane * 8];
                #pragma unroll
                for (int mi = 0; mi < 4; mi++) {
                    acc[mi][vi] = __builtin_amdgcn_mfma_f32_16x16x32_f16(ah[mi], bh, acc[mi][vi], 0, 0, 0);
                    acc[mi][vi] = __builtin_amdgcn_mfma_f32_16x16x32_f16(ah[mi], bl, acc[mi][vi], 0, 0, 0);
                }
            }
        }
    }

    // ---- sweep 2: stage Al(r0) Bh(r1), 4 GLL/wave ----
    {
        const _Float16* g2[4];
        #pragma unroll
        for (int j = 0; j < 4; j++) {
            int s = wid * 4 + j;          // 0..15
            int plane = s >> 3;           // 0 Al, 1 Bh
            int sub = s & 7;
            const _Float16* P = plane == 0 ? Xl : Wh;
            int row = (plane == 0 ? m0 : v0) + sub * 16 + lrow;
            g2[j] = P + (size_t)row * D_DIM + lq * 8;
        }
        for (int k0 = 0; k0 < D_DIM; k0 += 32) {
            __syncthreads();
            #pragma unroll
            for (int j = 0; j < 4; j++)
                GLL(g2[j] + k0, &lds[(wid * 4 + j) * 512]);
            __syncthreads();
            f16x8 al[4];
            #pragma unroll
            for (int i = 0; i < 4; i++)
                al[i] = *(const f16x8*)&lds[(wy * 4 + i) * 512 + lane * 8];
            #pragma unroll
            for (int vi = 0; vi < 4; vi++) {
                f16x8 bh = *(const f16x8*)&lds[(8 + wx * 4 + vi) * 512 + lane * 8];
                #pragma unroll
                for (int mi = 0; mi < 4; mi++)
                    acc[mi][vi] = __builtin_amdgcn_mfma_f32_16x16x32_f16(al[mi], bh, acc[mi][vi], 0, 0, 0);
            }
        }
    }

    // epilogue: C layout col=lane&15 (v), row=(lane>>4)*4+reg (m)
    float wnv[4];
    #pragma unroll
    for (int vi = 0; vi < 4; vi++) wnv[vi] = wnorm[v0 + (wx * 4 + vi) * 16 + lrow];

    #pragma unroll
    for (int mi = 0; mi < 4; mi++) {
        #pragma unroll
        for (int r = 0; r < 4; r++) {
            unsigned long long k = ~0ull;
            #pragma unroll
            for (int vi = 0; vi < 4; vi++) {
                int v = v0 + (wx * 4 + vi) * 16 + lrow;
                float s = wnv[vi] - 2.0f * acc[mi][vi][r];
                unsigned long long key = packkey(s, v);
                k = key < k ? key : k;
            }
            #pragma unroll
            for (int msk = 1; msk < 16; msk <<= 1) {
                unsigned long long o = __shfl_xor(k, msk, 64);
                k = o < k ? o : k;
            }
            if (lrow == 0) {
                int m = m0 + (wy * 4 + mi) * 16 + lq * 4 + r;
                // guarded atomic: best[m] is monotone decreasing, stale read only
                // causes a redundant atomic, never a skipped update
                if (k < best[m]) atomicMin(&best[m], k);
            }
        }
    }
}

// ---------------- K2a: extract idx, count per code ----------------
__global__ void k_count(const unsigned long long* __restrict__ best,
                        int* __restrict__ counts, float* __restrict__ out) {
    int m = blockIdx.x * 256 + threadIdx.x;
    int v = (int)(unsigned)(best[m] & 0xFFFFFFFFull);
    atomicAdd(&counts[v], 1);
    out[OFF_IDX + m] = (float)v;
}

// ---------------- K2b: exclusive prefix over 8192 counts ----------------
__global__ void k_prefix(const int* __restrict__ counts, int* __restrict__ offsets,
                         int* __restrict__ cursor) {
    __shared__ int tsum[256];
    int t = threadIdx.x;
    int local[32];
    int s = 0;
    #pragma unroll
    for (int i = 0; i < 32; i++) { local[i] = s; s += counts[t * 32 + i]; }
    tsum[t] = s;
    __syncthreads();
    if (t == 0) {
        int run = 0;
        for (int i = 0; i < 256; i++) { int c = tsum[i]; tsum[i] = run; run += c; }
    }
    __syncthreads();
    int base = tsum[t];
    #pragma unroll
    for (int i = 0; i < 32; i++) {
        int o = base + local[i];
        offsets[t * 32 + i] = o;
        cursor[t * 32 + i]  = o;
    }
}

// ---------------- K2c: fill bins ----------------
__global__ void k_fill(const unsigned long long* __restrict__ best,
                       int* __restrict__ cursor, int* __restrict__ bin) {
    int m = blockIdx.x * 256 + threadIdx.x;
    int v = (int)(unsigned)(best[m] & 0xFFFFFFFFull);
    int pos = atomicAdd(&cursor[v], 1);
    bin[pos] = m;
}

// ---------------- K2d: per-code reduction -> new_N, new_z_avg (no atomics) ----------------
__global__ void k_codes(const _Float16* __restrict__ Xh, const _Float16* __restrict__ Xl,
                        const float* __restrict__ N, const float* __restrict__ zavg,
                        const int* __restrict__ counts, const int* __restrict__ offsets,
                        const int* __restrict__ bin, float* __restrict__ out) {
    int v = blockIdx.x;
    int d = threadIdx.x;
    int cnt = counts[v];
    int off = offsets[v];
    float s = 0.0f;
    for (int r = 0; r < cnt; r++) {
        int m = bin[off + r];
        s += (float)Xh[(size_t)m * D_DIM + d] + (float)Xl[(size_t)m * D_DIM + d];
    }
    out[OFF_ZAVG + (size_t)v * D_DIM + d] = GAMMA_F * zavg[(size_t)v * D_DIM + d] + OMG_F * s;
    if (d == 0) out[OFF_NN + v] = GAMMA_F * N[v] + OMG_F * (float)cnt;
}

// ---------------- K3: quant_st + quant_diff (float4 along sp) ----------------
__global__ void k_quant(const float* __restrict__ X, const float* __restrict__ W,
                        const unsigned long long* __restrict__ best, float* __restrict__ out,
                        float* __restrict__ ws_scal) {
    int e4 = blockIdx.x * 256 + threadIdx.x;    // element/4 in (b, d, sp) order
    int e  = e4 * 4;
    int sp = e & 4095;
    int bd = e >> 12;
    int d  = bd & 255;
    int b  = bd >> 8;
    int mb = b * SPATIAL + sp;
    float4 x4 = *(const float4*)(X + e);
    float q[4];
    float p = 0.0f;
    #pragma unroll
    for (int j = 0; j < 4; j++) {
        int v = (int)(unsigned)(best[mb + j] & 0xFFFFFFFFull);
        float wv = W[(size_t)v * D_DIM + d];
        float xv = (j == 0) ? x4.x : (j == 1) ? x4.y : (j == 2) ? x4.z : x4.w;
        q[j] = (wv - xv) + xv;                 // straight-through
        float df = xv - wv;
        p = fmaf(df, df, p);
    }
    *(float4*)(out + OFF_QUANT + e) = make_float4(q[0], q[1], q[2], q[3]);
    #pragma unroll
    for (int msk = 32; msk > 0; msk >>= 1) p += __shfl_xor(p, msk, 64);
    __shared__ float red[4];
    int lane = threadIdx.x & 63, w = threadIdx.x >> 6;
    if (lane == 0) red[w] = p;
    __syncthreads();
    if (threadIdx.x == 0)
        atomicAdd(ws_scal, red[0] + red[1] + red[2] + red[3]);
}

// ---------------- K4a: n = sum(new_N); finalize quant_diff ----------------
__global__ void k_finalize_n(const float* __restrict__ outNN, float* __restrict__ ws_scal,
                             float* __restrict__ out_qdiff) {
    __shared__ float red[256];
    float s = 0.0f;
    for (int v = threadIdx.x; v < V_CODES; v += 256) s += outNN[v];
    red[threadIdx.x] = s;
    __syncthreads();
    #pragma unroll
    for (int t = 128; t > 0; t >>= 1) {
        if (threadIdx.x < t) red[threadIdx.x] += red[threadIdx.x + t];
        __syncthreads();
    }
    if (threadIdx.x == 0) {
        ws_scal[1] = red[0];
        out_qdiff[0] = ws_scal[0] * (1.0f / 8388608.0f);
    }
}

// ---------------- K4b: new_weight = new_z_avg / w ----------------
__global__ void k_weight(const float* __restrict__ zavg_out, const float* __restrict__ nn_out,
                         const float* __restrict__ ws_scal, float* __restrict__ out_w) {
    int i = blockIdx.x * 256 + threadIdx.x;
    int v = i >> 8;
    float n = ws_scal[1];
    float w = (nn_out[v] + EPS_F) / (n + VEPS_F) * n;
    out_w[i] = zavg_out[i] / w;
}

extern "C" void kernel_launch(void* const* d_in, const int* in_sizes, int n_in,
                              void* d_out, int out_size, void* d_ws, size_t ws_size,
                              hipStream_t stream) {
    const float* x    = (const float*)d_in[0];
    const float* w    = (const float*)d_in[1];
    const float* N    = (const float*)d_in[2];
    const float* zavg = (const float*)d_in[3];
    float* out = (float*)d_out;
    char*  wsb = (char*)d_ws;

    // workspace layout (bytes)
    float* ws_scal   = (float*)wsb;                      // 64 B   [0]=qdiff sum [1]=n
    int*   ws_counts = (int*)(wsb + 64);                 // 32 KB
    float* ws_wnorm  = (float*)(wsb + 32832);            // 32 KB
    int*   ws_off    = (int*)(wsb + 65600);              // 32 KB
    int*   ws_cur    = (int*)(wsb + 98368);              // 32 KB
    int*   ws_bin    = (int*)(wsb + 131136);             // 128 KB
    unsigned long long* ws_best = (unsigned long long*)(wsb + 262208);  // 256 KB
    _Float16* Xh = (_Float16*)(wsb + 524352);            // 16.78 MB
    _Float16* Xl = (_Float16*)(wsb + 524352 + 16777216);
    _Float16* Wh = (_Float16*)(wsb + 524352 + 2 * 16777216);  // 4.19 MB
    _Float16* Wl = (_Float16*)(wsb + 524352 + 2 * 16777216 + 4194304);
    // total ~42.5 MB

    hipMemsetAsync(wsb, 0, 32832, stream);                       // scal + counts
    hipMemsetAsync(ws_best, 0xFF, (size_t)M_ROWS * 8, stream);

    k_split_w<<<(V_CODES * D_DIM) / (256 * 8), 256, 0, stream>>>(w, Wh, Wl, ws_wnorm);
    k_split_x<<<1024, 256, 0, stream>>>(x, Xh, Xl);

    dim3 grid(V_CODES / 128, M_ROWS / 128);
    k_mfma_argmin<<<grid, 256, 0, stream>>>(Xh, Xl, Wh, Wl, ws_wnorm, ws_best);

    k_count  <<<M_ROWS / 256, 256, 0, stream>>>(ws_best, ws_counts, out);
    k_prefix <<<1, 256, 0, stream>>>(ws_counts, ws_off, ws_cur);
    k_fill   <<<M_ROWS / 256, 256, 0, stream>>>(ws_best, ws_cur, ws_bin);
    k_codes  <<<V_CODES, 256, 0, stream>>>(Xh, Xl, N, zavg, ws_counts, ws_off, ws_bin, out);
    k_quant  <<<NELEM / (256 * 4), 256, 0, stream>>>(x, w, ws_best, out, ws_scal);

    k_finalize_n<<<1, 256, 0, stream>>>(out + OFF_NN, ws_scal, out + OFF_QDIFF);
    k_weight <<<(V_CODES * D_DIM) / 256, 256, 0, stream>>>(out + OFF_ZAVG, out + OFF_NN, ws_scal, out + OFF_W);
}

// Round 6
// 1155.509 us; speedup vs baseline: 2.1942x; 2.1942x over previous
//
#include <hip/hip_runtime.h>

// ---------------- problem constants ----------------
#define V_CODES 8192
#define D_DIM   256
#define SPATIAL 4096            // 16*16*16
#define M_ROWS  32768           // 8 * 4096
#define NELEM   8388608         // M_ROWS * D_DIM

static constexpr float GAMMA_F = 0.99f;
static constexpr float OMG_F   = (float)(1.0 - 0.99);
static constexpr float EPS_F   = 1e-7f;
static constexpr float VEPS_F  = (float)(8192 * 1e-7);

// output layout (floats), concatenated in reference return order
static constexpr size_t OFF_QUANT = 0;            // 8388608  quant_st
static constexpr size_t OFF_IDX   = 8388608;      // 32768    enc_idx (stored as float)
static constexpr size_t OFF_QDIFF = 8421376;      // 1        quant_diff
static constexpr size_t OFF_NN    = 8421377;      // 8192     new_N
static constexpr size_t OFF_ZAVG  = 8429569;      // 2097152  new_z_avg
static constexpr size_t OFF_W     = 10526721;     // 2097152  new_weight

typedef _Float16 f16x8 __attribute__((ext_vector_type(8)));
typedef float    f32x4 __attribute__((ext_vector_type(4)));

// async global->LDS, 16B per lane; LDS dest is wave-uniform base + lane*16
#define GLL(gp, lp) __builtin_amdgcn_global_load_lds( \
    (const __attribute__((address_space(1))) unsigned int*)(gp), \
    (__attribute__((address_space(3))) unsigned int*)(lp), 16, 0, 0)

// ---------------- K0c: split W into fp16 hi/lo planes + fused row norms ----------------
__global__ void k_split_w(const float* __restrict__ W, _Float16* __restrict__ Wh,
                          _Float16* __restrict__ Wl, float* __restrict__ wnorm) {
    int t = blockIdx.x * 256 + threadIdx.x;
    size_t i8 = (size_t)t * 8;
    float4 a = *(const float4*)(W + i8);
    float4 b = *(const float4*)(W + i8 + 4);
    float v[8] = {a.x, a.y, a.z, a.w, b.x, b.y, b.z, b.w};
    f16x8 hi, lo;
    float s = 0.0f;
    #pragma unroll
    for (int j = 0; j < 8; j++) {
        _Float16 h = (_Float16)v[j];
        hi[j] = h;
        lo[j] = (_Float16)(v[j] - (float)h);
        s = fmaf(v[j], v[j], s);
    }
    *(f16x8*)(Wh + i8) = hi;
    *(f16x8*)(Wl + i8) = lo;
    #pragma unroll
    for (int msk = 1; msk < 32; msk <<= 1) s += __shfl_xor(s, msk, 64);
    if ((threadIdx.x & 31) == 0) wnorm[t >> 5] = s;
}

// ---------------- K0d: split + transpose X (b,k,sp) -> Xh/Xl (m, k) row-major ----------------
__global__ void k_split_x(const float* __restrict__ X, _Float16* __restrict__ Xh,
                          _Float16* __restrict__ Xl) {
    int bid  = blockIdx.x;            // 1024 blocks
    int lane = threadIdx.x & 63;
    int kg   = (bid & 1) * 4 + (threadIdx.x >> 6);   // 0..7 -> k base kg*32
    int m    = (bid >> 1) * 64 + lane;
    int b  = m >> 12;
    int sp = m & 4095;
    const float* src = X + (size_t)b * (D_DIM * SPATIAL) + (size_t)(kg * 32) * SPATIAL + sp;
    float v[32];
    #pragma unroll
    for (int j = 0; j < 32; j++) v[j] = src[(size_t)j * SPATIAL];   // coalesced across lanes
    _Float16* dh = Xh + (size_t)m * D_DIM + kg * 32;
    _Float16* dl = Xl + (size_t)m * D_DIM + kg * 32;
    #pragma unroll
    for (int c = 0; c < 4; c++) {
        f16x8 hi, lo;
        #pragma unroll
        for (int j = 0; j < 8; j++) {
            float x = v[c * 8 + j];
            _Float16 h = (_Float16)x;
            hi[j] = h;
            lo[j] = (_Float16)(x - (float)h);
        }
        *(f16x8*)(dh + c * 8) = hi;
        *(f16x8*)(dl + c * 8) = lo;
    }
}

// ---------------- K1: MFMA distance GEMM + argmin ----------------
// R3 structure (single sweep, (256,2), plain atomicMin) with 128m x 64v tile:
// 4 waves as 2x2 over (64m x 32v) each, acc 4x2, ~32 AGPR + ~64 VGPR -> 5 waves/SIMD target.
__device__ inline unsigned long long packkey(float s, int v) {
    unsigned u = __float_as_uint(s);
    u = (u & 0x80000000u) ? ~u : (u | 0x80000000u);
    return ((unsigned long long)u << 32) | (unsigned)v;
}

__global__ __launch_bounds__(256, 2) void k_mfma_argmin(
        const _Float16* __restrict__ Xh, const _Float16* __restrict__ Xl,
        const _Float16* __restrict__ Wh, const _Float16* __restrict__ Wl,
        const float* __restrict__ wnorm, unsigned long long* __restrict__ best) {
    // 24 LDS regions x 1 KB (16 rows x 32 k, fragment order):
    // 0-7 Ah, 8-15 Al (128 m-rows), 16-19 Bh, 20-23 Bl (64 v-rows)
    __shared__ __align__(16) _Float16 lds[12288];
    const int tid  = threadIdx.x;
    const int wid  = tid >> 6;
    const int lane = tid & 63;
    const int wy = wid >> 1, wx = wid & 1;   // wy: m-half (64 rows), wx: v-half (32 cols)
    const int lrow = lane & 15, lq = lane >> 4;
    const int m0 = blockIdx.y * 128;
    const int v0 = blockIdx.x * 64;

    f32x4 acc[4][2] = {};

    // each wave stages 6 regions: r = wid*6 + j
    const _Float16* g[6];
    #pragma unroll
    for (int j = 0; j < 6; j++) {
        int r = wid * 6 + j;
        const _Float16* P;
        int rowb;
        if (r < 8)       { P = Xh; rowb = m0 + r * 16; }
        else if (r < 16) { P = Xl; rowb = m0 + (r - 8) * 16; }
        else if (r < 20) { P = Wh; rowb = v0 + (r - 16) * 16; }
        else             { P = Wl; rowb = v0 + (r - 20) * 16; }
        g[j] = P + (size_t)(rowb + lrow) * D_DIM + lq * 8;
    }

    for (int k0 = 0; k0 < D_DIM; k0 += 32) {
        __syncthreads();
        #pragma unroll
        for (int j = 0; j < 6; j++)
            GLL(g[j] + k0, &lds[(wid * 6 + j) * 512]);
        __syncthreads();
        f16x8 ah[4], al[4];
        #pragma unroll
        for (int i = 0; i < 4; i++) {
            ah[i] = *(const f16x8*)&lds[(     wy * 4 + i) * 512 + lane * 8];
            al[i] = *(const f16x8*)&lds[(8 +  wy * 4 + i) * 512 + lane * 8];
        }
        #pragma unroll
        for (int vi = 0; vi < 2; vi++) {
            f16x8 bh = *(const f16x8*)&lds[(16 + wx * 2 + vi) * 512 + lane * 8];
            f16x8 bl = *(const f16x8*)&lds[(20 + wx * 2 + vi) * 512 + lane * 8];
            #pragma unroll
            for (int mi = 0; mi < 4; mi++) {
                acc[mi][vi] = __builtin_amdgcn_mfma_f32_16x16x32_f16(ah[mi], bh, acc[mi][vi], 0, 0, 0);
                acc[mi][vi] = __builtin_amdgcn_mfma_f32_16x16x32_f16(al[mi], bh, acc[mi][vi], 0, 0, 0);
                acc[mi][vi] = __builtin_amdgcn_mfma_f32_16x16x32_f16(ah[mi], bl, acc[mi][vi], 0, 0, 0);
            }
        }
    }

    // epilogue: C layout col=lane&15 (v), row=(lane>>4)*4+reg (m)
    float wnv[2];
    #pragma unroll
    for (int vi = 0; vi < 2; vi++) wnv[vi] = wnorm[v0 + (wx * 2 + vi) * 16 + lrow];

    #pragma unroll
    for (int mi = 0; mi < 4; mi++) {
        #pragma unroll
        for (int r = 0; r < 4; r++) {
            unsigned long long k = ~0ull;
            #pragma unroll
            for (int vi = 0; vi < 2; vi++) {
                int v = v0 + (wx * 2 + vi) * 16 + lrow;
                float s = wnv[vi] - 2.0f * acc[mi][vi][r];
                unsigned long long key = packkey(s, v);
                k = key < k ? key : k;
            }
            #pragma unroll
            for (int msk = 1; msk < 16; msk <<= 1) {
                unsigned long long o = __shfl_xor(k, msk, 64);
                k = o < k ? o : k;
            }
            if (lrow == 0) {
                int m = m0 + (wy * 4 + mi) * 16 + lq * 4 + r;
                atomicMin(&best[m], k);
            }
        }
    }
}

// ---------------- K2a: extract idx, count per code ----------------
__global__ void k_count(const unsigned long long* __restrict__ best,
                        int* __restrict__ counts, float* __restrict__ out) {
    int m = blockIdx.x * 256 + threadIdx.x;
    int v = (int)(unsigned)(best[m] & 0xFFFFFFFFull);
    atomicAdd(&counts[v], 1);
    out[OFF_IDX + m] = (float)v;
}

// ---------------- K2b: exclusive prefix over 8192 counts ----------------
__global__ void k_prefix(const int* __restrict__ counts, int* __restrict__ offsets,
                         int* __restrict__ cursor) {
    __shared__ int tsum[256];
    int t = threadIdx.x;
    int local[32];
    int s = 0;
    #pragma unroll
    for (int i = 0; i < 32; i++) { local[i] = s; s += counts[t * 32 + i]; }
    tsum[t] = s;
    __syncthreads();
    if (t == 0) {
        int run = 0;
        for (int i = 0; i < 256; i++) { int c = tsum[i]; tsum[i] = run; run += c; }
    }
    __syncthreads();
    int base = tsum[t];
    #pragma unroll
    for (int i = 0; i < 32; i++) {
        int o = base + local[i];
        offsets[t * 32 + i] = o;
        cursor[t * 32 + i]  = o;
    }
}

// ---------------- K2c: fill bins ----------------
__global__ void k_fill(const unsigned long long* __restrict__ best,
                       int* __restrict__ cursor, int* __restrict__ bin) {
    int m = blockIdx.x * 256 + threadIdx.x;
    int v = (int)(unsigned)(best[m] & 0xFFFFFFFFull);
    int pos = atomicAdd(&cursor[v], 1);
    bin[pos] = m;
}

// ---------------- K2d: per-code reduction -> new_N, new_z_avg (no atomics) ----------------
__global__ void k_codes(const _Float16* __restrict__ Xh, const _Float16* __restrict__ Xl,
                        const float* __restrict__ N, const float* __restrict__ zavg,
                        const int* __restrict__ counts, const int* __restrict__ offsets,
                        const int* __restrict__ bin, float* __restrict__ out) {
    int v = blockIdx.x;
    int d = threadIdx.x;
    int cnt = counts[v];
    int off = offsets[v];
    float s = 0.0f;
    for (int r = 0; r < cnt; r++) {
        int m = bin[off + r];
        s += (float)Xh[(size_t)m * D_DIM + d] + (float)Xl[(size_t)m * D_DIM + d];
    }
    out[OFF_ZAVG + (size_t)v * D_DIM + d] = GAMMA_F * zavg[(size_t)v * D_DIM + d] + OMG_F * s;
    if (d == 0) out[OFF_NN + v] = GAMMA_F * N[v] + OMG_F * (float)cnt;
}

// ---------------- K3: quant_st + quant_diff (float4 along sp) ----------------
__global__ void k_quant(const float* __restrict__ X, const float* __restrict__ W,
                        const unsigned long long* __restrict__ best, float* __restrict__ out,
                        float* __restrict__ ws_scal) {
    int e4 = blockIdx.x * 256 + threadIdx.x;    // element/4 in (b, d, sp) order
    int e  = e4 * 4;
    int sp = e & 4095;
    int bd = e >> 12;
    int d  = bd & 255;
    int b  = bd >> 8;
    int mb = b * SPATIAL + sp;
    float4 x4 = *(const float4*)(X + e);
    float q[4];
    float p = 0.0f;
    #pragma unroll
    for (int j = 0; j < 4; j++) {
        int v = (int)(unsigned)(best[mb + j] & 0xFFFFFFFFull);
        float wv = W[(size_t)v * D_DIM + d];
        float xv = (j == 0) ? x4.x : (j == 1) ? x4.y : (j == 2) ? x4.z : x4.w;
        q[j] = (wv - xv) + xv;                 // straight-through
        float df = xv - wv;
        p = fmaf(df, df, p);
    }
    *(float4*)(out + OFF_QUANT + e) = make_float4(q[0], q[1], q[2], q[3]);
    #pragma unroll
    for (int msk = 32; msk > 0; msk >>= 1) p += __shfl_xor(p, msk, 64);
    __shared__ float red[4];
    int lane = threadIdx.x & 63, w = threadIdx.x >> 6;
    if (lane == 0) red[w] = p;
    __syncthreads();
    if (threadIdx.x == 0)
        atomicAdd(ws_scal, red[0] + red[1] + red[2] + red[3]);
}

// ---------------- K4a: n = sum(new_N); finalize quant_diff ----------------
__global__ void k_finalize_n(const float* __restrict__ outNN, float* __restrict__ ws_scal,
                             float* __restrict__ out_qdiff) {
    __shared__ float red[256];
    float s = 0.0f;
    for (int v = threadIdx.x; v < V_CODES; v += 256) s += outNN[v];
    red[threadIdx.x] = s;
    __syncthreads();
    #pragma unroll
    for (int t = 128; t > 0; t >>= 1) {
        if (threadIdx.x < t) red[threadIdx.x] += red[threadIdx.x + t];
        __syncthreads();
    }
    if (threadIdx.x == 0) {
        ws_scal[1] = red[0];
        out_qdiff[0] = ws_scal[0] * (1.0f / 8388608.0f);
    }
}

// ---------------- K4b: new_weight = new_z_avg / w ----------------
__global__ void k_weight(const float* __restrict__ zavg_out, const float* __restrict__ nn_out,
                         const float* __restrict__ ws_scal, float* __restrict__ out_w) {
    int i = blockIdx.x * 256 + threadIdx.x;
    int v = i >> 8;
    float n = ws_scal[1];
    float w = (nn_out[v] + EPS_F) / (n + VEPS_F) * n;
    out_w[i] = zavg_out[i] / w;
}

extern "C" void kernel_launch(void* const* d_in, const int* in_sizes, int n_in,
                              void* d_out, int out_size, void* d_ws, size_t ws_size,
                              hipStream_t stream) {
    const float* x    = (const float*)d_in[0];
    const float* w    = (const float*)d_in[1];
    const float* N    = (const float*)d_in[2];
    const float* zavg = (const float*)d_in[3];
    float* out = (float*)d_out;
    char*  wsb = (char*)d_ws;

    // workspace layout (bytes)
    float* ws_scal   = (float*)wsb;                      // 64 B   [0]=qdiff sum [1]=n
    int*   ws_counts = (int*)(wsb + 64);                 // 32 KB
    float* ws_wnorm  = (float*)(wsb + 32832);            // 32 KB
    int*   ws_off    = (int*)(wsb + 65600);              // 32 KB
    int*   ws_cur    = (int*)(wsb + 98368);              // 32 KB
    int*   ws_bin    = (int*)(wsb + 131136);             // 128 KB
    unsigned long long* ws_best = (unsigned long long*)(wsb + 262208);  // 256 KB
    _Float16* Xh = (_Float16*)(wsb + 524352);            // 16.78 MB
    _Float16* Xl = (_Float16*)(wsb + 524352 + 16777216);
    _Float16* Wh = (_Float16*)(wsb + 524352 + 2 * 16777216);  // 4.19 MB
    _Float16* Wl = (_Float16*)(wsb + 524352 + 2 * 16777216 + 4194304);
    // total ~42.5 MB

    hipMemsetAsync(wsb, 0, 32832, stream);                       // scal + counts
    hipMemsetAsync(ws_best, 0xFF, (size_t)M_ROWS * 8, stream);

    k_split_w<<<(V_CODES * D_DIM) / (256 * 8), 256, 0, stream>>>(w, Wh, Wl, ws_wnorm);
    k_split_x<<<1024, 256, 0, stream>>>(x, Xh, Xl);

    dim3 grid(V_CODES / 64, M_ROWS / 128);
    k_mfma_argmin<<<grid, 256, 0, stream>>>(Xh, Xl, Wh, Wl, ws_wnorm, ws_best);

    k_count  <<<M_ROWS / 256, 256, 0, stream>>>(ws_best, ws_counts, out);
    k_prefix <<<1, 256, 0, stream>>>(ws_counts, ws_off, ws_cur);
    k_fill   <<<M_ROWS / 256, 256, 0, stream>>>(ws_best, ws_cur, ws_bin);
    k_codes  <<<V_CODES, 256, 0, stream>>>(Xh, Xl, N, zavg, ws_counts, ws_off, ws_bin, out);
    k_quant  <<<NELEM / (256 * 4), 256, 0, stream>>>(x, w, ws_best, out, ws_scal);

    k_finalize_n<<<1, 256, 0, stream>>>(out + OFF_NN, ws_scal, out + OFF_QDIFF);
    k_weight <<<(V_CODES * D_DIM) / 256, 256, 0, stream>>>(out + OFF_ZAVG, out + OFF_NN, ws_scal, out + OFF_W);
}